// Round 1
// baseline (538.104 us; speedup 1.0000x reference)
//
#include <hip/hip_runtime.h>
#include <hip/hip_bf16.h>

// Problem constants: B=4, S=2048, E=1024, H=16, D=64
#define BB 4
#define SS 2048
#define EE 1024
#define HH 16
#define DD 64
#define MM (BB*SS)   // 8192 rows

using f16x8 = __attribute__((ext_vector_type(8))) _Float16;
using f32x4 = __attribute__((ext_vector_type(4))) float;

// ---- staging helpers: load 8 elems from global, store fp16x8 to LDS ----
__device__ __forceinline__ void stage8(_Float16* dst, const float* src) {
    const float4 v0 = *(const float4*)src;
    const float4 v1 = *(const float4*)(src + 4);
    f16x8 h;
    h[0] = (_Float16)v0.x; h[1] = (_Float16)v0.y;
    h[2] = (_Float16)v0.z; h[3] = (_Float16)v0.w;
    h[4] = (_Float16)v1.x; h[5] = (_Float16)v1.y;
    h[6] = (_Float16)v1.z; h[7] = (_Float16)v1.w;
    *(f16x8*)dst = h;
}
__device__ __forceinline__ void stage8(_Float16* dst, const _Float16* src) {
    *(f16x8*)dst = *(const f16x8*)src;
}

// ---- GEMM: C[M,N] = A[M,K] @ Bw[N,K]^T  (x @ W.T), fp16 MFMA, fp32 accum ----
// 128x128 tile, BK=32, 256 threads (4 waves in 2x2), 4x4 16x16x32 MFMAs/wave.
template <typename TA, typename TC>
__global__ __launch_bounds__(256) void gemm_bt(const TA* __restrict__ A,
                                               const float* __restrict__ Bw,
                                               TC* __restrict__ C,
                                               int M, int N, int K) {
    constexpr int BM = 128, BN = 128, BK = 32;
    __shared__ alignas(16) _Float16 As[BM * BK];  // stride 32 elems (64B): conflict-free for frag reads
    __shared__ alignas(16) _Float16 Bs[BN * BK];

    const int tid  = threadIdx.x;
    const int lane = tid & 63;
    const int wave = tid >> 6;
    const int wm   = (wave >> 1) * 64;   // wave row offset in tile
    const int wn   = (wave & 1) * 64;    // wave col offset in tile
    const int quad = lane >> 4;
    const int c    = lane & 15;
    const int m0   = blockIdx.x * BM;
    const int n0   = blockIdx.y * BN;

    f32x4 acc[4][4] = {};

    for (int k0 = 0; k0 < K; k0 += BK) {
        // stage A and B tiles: 512 chunks of 8 elems each, 2 per thread per tile
#pragma unroll
        for (int p = 0; p < 2; ++p) {
            int ch  = tid + p * 256;       // 0..511
            int row = ch >> 2;             // 0..127
            int kc  = (ch & 3) * 8;        // 0..24
            stage8(&As[row * BK + kc], A  + (m0 + row) * K + k0 + kc);
            stage8(&Bs[row * BK + kc], Bw + (n0 + row) * K + k0 + kc);
        }
        __syncthreads();

        f16x8 af[4], bf[4];
#pragma unroll
        for (int i = 0; i < 4; ++i)
            af[i] = *(const f16x8*)&As[(wm + i * 16 + c) * BK + quad * 8];
#pragma unroll
        for (int j = 0; j < 4; ++j)
            bf[j] = *(const f16x8*)&Bs[(wn + j * 16 + c) * BK + quad * 8];
#pragma unroll
        for (int i = 0; i < 4; ++i)
#pragma unroll
            for (int j = 0; j < 4; ++j)
                acc[i][j] = __builtin_amdgcn_mfma_f32_16x16x32_f16(af[i], bf[j], acc[i][j], 0, 0, 0);
        __syncthreads();
    }

    // epilogue: C/D layout col = lane&15, row = quad*4 + r
#pragma unroll
    for (int i = 0; i < 4; ++i)
#pragma unroll
        for (int j = 0; j < 4; ++j)
#pragma unroll
            for (int r = 0; r < 4; ++r) {
                int row = m0 + wm + i * 16 + quad * 4 + r;
                int col = n0 + wn + j * 16 + c;
                C[row * N + col] = (TC)acc[i][j][r];
            }
}

// ---- Flash attention: per-block 128 q-rows of one (b,h); K/V tiles of 64 ----
// Q,K,V are fp16 (B*S, E) row-major; head h = cols [h*64, h*64+64).
// O written fp16 same layout.
__global__ __launch_bounds__(256) void attn_kernel(const _Float16* __restrict__ Q,
                                                   const _Float16* __restrict__ K,
                                                   const _Float16* __restrict__ V,
                                                   _Float16* __restrict__ O) {
    constexpr int KT = 64;          // k/v tile rows
    constexpr int LQ = 72;          // padded LDS strides (mult of 8 elems, +8 pad)
    __shared__ alignas(16) _Float16 Qs[128 * LQ];      // 18 KB
    __shared__ alignas(16) _Float16 Ks[KT * LQ];       // 9 KB
    __shared__ alignas(16) _Float16 Vts[DD * LQ];      // 9 KB  (V^T: [d][s])
    __shared__ alignas(16) _Float16 Ps[4][32 * LQ];    // 18 KB (per-wave P)

    const int tid  = threadIdx.x;
    const int lane = tid & 63;
    const int wave = tid >> 6;
    const int quad = lane >> 4;
    const int c    = lane & 15;
    const int bh   = blockIdx.y;           // 0..63
    const int b    = bh >> 4, h = bh & 15;
    const int q0   = blockIdx.x * 128;

    const _Float16* Qg = Q + (b * SS + q0) * EE + h * DD;
    const _Float16* Kg = K + (b * SS) * EE + h * DD;
    const _Float16* Vg = V + (b * SS) * EE + h * DD;

    // stage Q tile once: 1024 chunks (128 rows x 8 kc)
#pragma unroll
    for (int p = 0; p < 4; ++p) {
        int ch  = tid + p * 256;
        int row = ch >> 3;
        int kc  = (ch & 7) * 8;
        *(f16x8*)&Qs[row * LQ + kc] = *(const f16x8*)&Qg[row * EE + kc];
    }

    float m_st[2][4], l_st[2][4];
    f32x4 o_acc[2][4] = {};
#pragma unroll
    for (int i = 0; i < 2; ++i)
#pragma unroll
        for (int r = 0; r < 4; ++r) { m_st[i][r] = -INFINITY; l_st[i][r] = 0.f; }

    for (int s0 = 0; s0 < SS; s0 += KT) {
        __syncthreads();   // also covers initial Q staging
        // stage K tile: 512 chunks (64 rows x 8 kc)
#pragma unroll
        for (int p = 0; p < 2; ++p) {
            int ch  = tid + p * 256;
            int row = ch >> 3;
            int kc  = (ch & 7) * 8;
            *(f16x8*)&Ks[row * LQ + kc] = *(const f16x8*)&Kg[(s0 + row) * EE + kc];
        }
        // stage V transposed: lane-consecutive d → coalesced column reads
#pragma unroll
        for (int p = 0; p < 2; ++p) {
            int ch  = tid + p * 256;     // 0..511
            int d   = ch & 63;
            int scg = ch >> 6;           // 0..7
            f16x8 hv;
#pragma unroll
            for (int j = 0; j < 8; ++j)
                hv[j] = Vg[(s0 + scg * 8 + j) * EE + d];
            *(f16x8*)&Vts[d * LQ + scg * 8] = hv;
        }
        __syncthreads();

        // ---- S = Q @ K^T for this wave's 32 q-rows x 64 k-cols ----
        f32x4 sacc[2][4] = {};
#pragma unroll
        for (int kt = 0; kt < 2; ++kt) {
            f16x8 aq[2], bk[4];
#pragma unroll
            for (int i = 0; i < 2; ++i)
                aq[i] = *(const f16x8*)&Qs[(wave * 32 + i * 16 + c) * LQ + kt * 32 + quad * 8];
#pragma unroll
            for (int j = 0; j < 4; ++j)
                bk[j] = *(const f16x8*)&Ks[(j * 16 + c) * LQ + kt * 32 + quad * 8];
#pragma unroll
            for (int i = 0; i < 2; ++i)
#pragma unroll
                for (int j = 0; j < 4; ++j)
                    sacc[i][j] = __builtin_amdgcn_mfma_f32_16x16x32_f16(aq[i], bk[j], sacc[i][j], 0, 0, 0);
        }

        // ---- online softmax (scale = 1/sqrt(64) = 0.125) ----
#pragma unroll
        for (int i = 0; i < 2; ++i) {
#pragma unroll
            for (int r = 0; r < 4; ++r) {
                float mt = -INFINITY;
#pragma unroll
                for (int j = 0; j < 4; ++j) mt = fmaxf(mt, sacc[i][j][r]);
                mt = fmaxf(mt, __shfl_xor(mt, 1));
                mt = fmaxf(mt, __shfl_xor(mt, 2));
                mt = fmaxf(mt, __shfl_xor(mt, 4));
                mt = fmaxf(mt, __shfl_xor(mt, 8));
                mt *= 0.125f;
                float mnew = fmaxf(m_st[i][r], mt);
                float al   = __expf(m_st[i][r] - mnew);
                m_st[i][r] = mnew;
                float rs = 0.f;
#pragma unroll
                for (int j = 0; j < 4; ++j) {
                    float pv = __expf(sacc[i][j][r] * 0.125f - mnew);
                    sacc[i][j][r] = pv;   // reuse as P
                    rs += pv;
                }
                rs += __shfl_xor(rs, 1);
                rs += __shfl_xor(rs, 2);
                rs += __shfl_xor(rs, 4);
                rs += __shfl_xor(rs, 8);
                l_st[i][r] = l_st[i][r] * al + rs;
#pragma unroll
                for (int n = 0; n < 4; ++n) o_acc[i][n][r] *= al;
            }
        }

        // ---- write P (C-layout) to per-wave LDS as fp16 ----
#pragma unroll
        for (int i = 0; i < 2; ++i)
#pragma unroll
            for (int j = 0; j < 4; ++j)
#pragma unroll
                for (int r = 0; r < 4; ++r)
                    Ps[wave][(i * 16 + quad * 4 + r) * LQ + j * 16 + c] = (_Float16)sacc[i][j][r];

        // ---- O += P @ V  (P from LDS in A-layout, V^T gives contiguous b_frag) ----
#pragma unroll
        for (int kt = 0; kt < 2; ++kt) {
            f16x8 pa[2], vb[4];
#pragma unroll
            for (int i = 0; i < 2; ++i)
                pa[i] = *(const f16x8*)&Ps[wave][(i * 16 + c) * LQ + kt * 32 + quad * 8];
#pragma unroll
            for (int n = 0; n < 4; ++n)
                vb[n] = *(const f16x8*)&Vts[(n * 16 + c) * LQ + kt * 32 + quad * 8];
#pragma unroll
            for (int i = 0; i < 2; ++i)
#pragma unroll
                for (int n = 0; n < 4; ++n)
                    o_acc[i][n] = __builtin_amdgcn_mfma_f32_16x16x32_f16(pa[i], vb[n], o_acc[i][n], 0, 0, 0);
        }
    }

    // ---- epilogue: O = o_acc / l ----
    _Float16* Og = O + (b * SS + q0) * EE + h * DD;
#pragma unroll
    for (int i = 0; i < 2; ++i)
#pragma unroll
        for (int n = 0; n < 4; ++n)
#pragma unroll
            for (int r = 0; r < 4; ++r) {
                int row = wave * 32 + i * 16 + quad * 4 + r;
                float v = o_acc[i][n][r] / l_st[i][r];
                Og[row * EE + n * 16 + c] = (_Float16)v;
            }
}

extern "C" void kernel_launch(void* const* d_in, const int* in_sizes, int n_in,
                              void* d_out, int out_size, void* d_ws, size_t ws_size,
                              hipStream_t stream) {
    const float* query = (const float*)d_in[0];
    const float* key   = (const float*)d_in[1];
    const float* value = (const float*)d_in[2];
    const float* Wq    = (const float*)d_in[3];
    const float* Wk    = (const float*)d_in[4];
    const float* Wv    = (const float*)d_in[5];
    const float* Wo    = (const float*)d_in[6];
    float* out = (float*)d_out;

    const int NE = MM * EE;  // 8388608 elements per activation
    _Float16* Qw = (_Float16*)d_ws;
    _Float16* Kw = Qw + NE;
    _Float16* Vw = Kw + NE;
    _Float16* Ow = Vw + NE;   // total 64 MiB of ws

    dim3 gg(MM / 128, EE / 128);   // 64 x 8
    dim3 blk(256);

    // projections: Q = query @ Wq.T, etc.  (fp32 in, fp16 out)
    gemm_bt<float, _Float16><<<gg, blk, 0, stream>>>(query, Wq, Qw, MM, EE, EE);
    gemm_bt<float, _Float16><<<gg, blk, 0, stream>>>(key,   Wk, Kw, MM, EE, EE);
    gemm_bt<float, _Float16><<<gg, blk, 0, stream>>>(value, Wv, Vw, MM, EE, EE);

    // attention: 16 q-tiles x 64 (b,h) pairs
    attn_kernel<<<dim3(SS / 128, BB * HH), blk, 0, stream>>>(Qw, Kw, Vw, Ow);

    // output projection: out = O @ Wo.T  (fp16 in, fp32 out)
    gemm_bt<_Float16, float><<<gg, blk, 0, stream>>>(Ow, Wo, out, MM, EE, EE);
}

// Round 2
// 418.458 us; speedup vs baseline: 1.2859x; 1.2859x over previous
//
#include <hip/hip_runtime.h>
#include <hip/hip_bf16.h>

// Problem constants: B=4, S=2048, E=1024, H=16, D=64
#define BB 4
#define SS 2048
#define EE 1024
#define HH 16
#define DD 64
#define MM (BB*SS)   // 8192 rows

using f16x8 = __attribute__((ext_vector_type(8))) _Float16;
using f16x4 = __attribute__((ext_vector_type(4))) _Float16;
using f32x4 = __attribute__((ext_vector_type(4))) float;

typedef __attribute__((address_space(3))) void       as3_void;
typedef const __attribute__((address_space(1))) void as1_cvoid;

// async global->LDS, 16B per lane; lds must be wave-uniform base (HW adds lane*16)
__device__ __forceinline__ void async16(void* lds, const void* g) {
    __builtin_amdgcn_global_load_lds((as1_cvoid*)g, (as3_void*)lds, 16, 0, 0);
}

// ---- fp32 -> fp16 convert, 8 elems/thread (16B stores) ----
__global__ __launch_bounds__(256) void cvt_kernel(const float* __restrict__ s,
                                                  _Float16* __restrict__ d, int n8) {
    int i = blockIdx.x * 256 + threadIdx.x;
    if (i < n8) {
        const float4* s4 = (const float4*)s;
        float4 v0 = s4[2 * i], v1 = s4[2 * i + 1];
        f16x8 h;
        h[0] = (_Float16)v0.x; h[1] = (_Float16)v0.y;
        h[2] = (_Float16)v0.z; h[3] = (_Float16)v0.w;
        h[4] = (_Float16)v1.x; h[5] = (_Float16)v1.y;
        h[6] = (_Float16)v1.z; h[7] = (_Float16)v1.w;
        ((f16x8*)d)[i] = h;
    }
}

// ---- GEMM: C[M,N] = A[M,K] @ Bw[N,K]^T, fp16 in (global_load_lds staging) ----
// 128x128 tile, BK=32, 256 threads (4 waves 2x2), 4x4 16x16x32 MFMAs/wave.
template <typename TC>
__global__ __launch_bounds__(256) void gemm_bt_f16(const _Float16* __restrict__ A,
                                                   const _Float16* __restrict__ Bw,
                                                   TC* __restrict__ C,
                                                   int M, int N, int K) {
    constexpr int BM = 128, BN = 128, BK = 32;
    __shared__ alignas(16) _Float16 As[BM * BK];  // 8KB, row-major stride 32 (m97 layout)
    __shared__ alignas(16) _Float16 Bs[BN * BK];

    const int tid  = threadIdx.x;
    const int lane = tid & 63;
    const int wave = tid >> 6;
    const int wm   = (wave >> 1) * 64;
    const int wn   = (wave & 1) * 64;
    const int quad = lane >> 4;
    const int c    = lane & 15;
    const int m0   = blockIdx.x * BM;
    const int n0   = blockIdx.y * BN;

    f32x4 acc[4][4] = {};

    for (int k0 = 0; k0 < K; k0 += BK) {
        // stage A,B tiles: 512 chunks of 16B each; chunk idx -> row=idx>>2, kc=(idx&3)*8
#pragma unroll
        for (int p = 0; p < 2; ++p) {
            int idx = (p * 4 + wave) * 64 + lane;    // 0..511
            int row = idx >> 2, kc = (idx & 3) * 8;
            async16(As + (p * 4 + wave) * 512, A  + (size_t)(m0 + row) * K + k0 + kc);
            async16(Bs + (p * 4 + wave) * 512, Bw + (size_t)(n0 + row) * K + k0 + kc);
        }
        __syncthreads();   // drains vmcnt(0) -> staging complete

        f16x8 af[4], bf[4];
#pragma unroll
        for (int i = 0; i < 4; ++i)
            af[i] = *(const f16x8*)&As[(wm + i * 16 + c) * BK + quad * 8];
#pragma unroll
        for (int j = 0; j < 4; ++j)
            bf[j] = *(const f16x8*)&Bs[(wn + j * 16 + c) * BK + quad * 8];
#pragma unroll
        for (int i = 0; i < 4; ++i)
#pragma unroll
            for (int j = 0; j < 4; ++j)
                acc[i][j] = __builtin_amdgcn_mfma_f32_16x16x32_f16(af[i], bf[j], acc[i][j], 0, 0, 0);
        __syncthreads();
    }

    // epilogue: C/D layout col=lane&15, row=quad*4+r
#pragma unroll
    for (int i = 0; i < 4; ++i)
#pragma unroll
        for (int j = 0; j < 4; ++j)
#pragma unroll
            for (int r = 0; r < 4; ++r) {
                int row = m0 + wm + i * 16 + quad * 4 + r;
                int col = n0 + wn + j * 16 + c;
                C[(size_t)row * N + col] = (TC)acc[i][j][r];
            }
}

// ---- Flash attention, transposed-S formulation ----
// S^T = K·Q^T (softmax stats lane-local in q=lane&15), O^T = V^T·P^T.
// P overlays the dead Ks region (PV in two 16-row q halves). LDS = 36KB -> 4 blocks/CU.
__global__ __launch_bounds__(256, 4) void attn_kernel(const _Float16* __restrict__ Q,
                                                      const _Float16* __restrict__ K,
                                                      const _Float16* __restrict__ V,
                                                      _Float16* __restrict__ O) {
    constexpr int KT = 64, LQ = 72, LK = 72, LV = 72, LP = 72;
    __shared__ alignas(16) _Float16 smem[(128 + 64 + 64) * 72];   // 36 KB
    _Float16* Qs  = smem;                 // [128][72] q-rows x d
    _Float16* KPs = smem + 128 * 72;      // [64][72]  k-rows x d; later P[q_local][k]
    _Float16* Vts = smem + 192 * 72;      // [64][72]  V^T: d x s

    const int tid  = threadIdx.x;
    const int lane = tid & 63;
    const int wave = tid >> 6;
    const int quad = lane >> 4;
    const int c    = lane & 15;
    const int bh   = blockIdx.y;          // 0..63
    const int b    = bh >> 4, h = bh & 15;
    const int q0   = blockIdx.x * 128;

    const _Float16* Qg = Q + (size_t)(b * SS + q0) * EE + h * DD;
    const _Float16* Kg = K + (size_t)(b * SS) * EE + h * DD;
    const _Float16* Vg = V + (size_t)(b * SS) * EE + h * DD;

    // stage Q tile once: 1024 x 16B chunks
#pragma unroll
    for (int p = 0; p < 4; ++p) {
        int ch = tid + p * 256;
        int row = ch >> 3, kc = (ch & 7) * 8;
        *(f16x8*)&Qs[row * LQ + kc] = *(const f16x8*)&Qg[(size_t)row * EE + kc];
    }

    const float cs = 0.125f * 1.44269504f;   // sm_scale * log2(e)
    float m2[2] = {-INFINITY, -INFINITY};    // running max, log2 domain, per q-tile
    float l[2]  = {0.f, 0.f};
    f32x4 o_acc[2][4] = {};                  // O^T: [q-tile i][d-tile dt]

    for (int s0 = 0; s0 < SS; s0 += KT) {
        __syncthreads();   // prev tile's PV done -> KPs/Vts free (also covers Q staging)
        // stage K tile
#pragma unroll
        for (int p = 0; p < 2; ++p) {
            int ch = tid + p * 256;
            int row = ch >> 3, kc = (ch & 7) * 8;
            *(f16x8*)&KPs[row * LK + kc] = *(const f16x8*)&Kg[(size_t)(s0 + row) * EE + kc];
        }
        // stage V transposed (coalesced 2B column loads)
#pragma unroll
        for (int p = 0; p < 2; ++p) {
            int ch = tid + p * 256;
            int d = ch & 63, scg = ch >> 6;
            f16x8 hv;
#pragma unroll
            for (int j = 0; j < 8; ++j)
                hv[j] = Vg[(size_t)(s0 + scg * 8 + j) * EE + d];
            *(f16x8*)&Vts[d * LV + scg * 8] = hv;
        }
        __syncthreads();

        // ---- S^T = K·Q^T : A=K rows (m=k), B=Q rows (n=q), K-dim=d ----
        f32x4 sacc[2][4] = {};   // [q-tile i][k-tile j]; col=q=c, row=k=j*16+quad*4+r
#pragma unroll
        for (int kt = 0; kt < 2; ++kt) {
            f16x8 ak[4], bq[2];
#pragma unroll
            for (int j = 0; j < 4; ++j)
                ak[j] = *(const f16x8*)&KPs[(j * 16 + c) * LK + kt * 32 + quad * 8];
#pragma unroll
            for (int i = 0; i < 2; ++i)
                bq[i] = *(const f16x8*)&Qs[(wave * 32 + i * 16 + c) * LQ + kt * 32 + quad * 8];
#pragma unroll
            for (int i = 0; i < 2; ++i)
#pragma unroll
                for (int j = 0; j < 4; ++j)
                    sacc[i][j] = __builtin_amdgcn_mfma_f32_16x16x32_f16(ak[j], bq[i], sacc[i][j], 0, 0, 0);
        }

        // ---- online softmax: 16 in-lane values + 2 cross-quad shuffles per q-tile ----
#pragma unroll
        for (int i = 0; i < 2; ++i) {
            float mt = sacc[i][0][0];
#pragma unroll
            for (int j = 0; j < 4; ++j)
#pragma unroll
                for (int r = 0; r < 4; ++r) mt = fmaxf(mt, sacc[i][j][r]);
            mt = fmaxf(mt, __shfl_xor(mt, 16));
            mt = fmaxf(mt, __shfl_xor(mt, 32));
            float mnew = fmaxf(m2[i], mt * cs);
            float al   = __builtin_amdgcn_exp2f(m2[i] - mnew);
            m2[i] = mnew;
            float rs = 0.f;
#pragma unroll
            for (int j = 0; j < 4; ++j)
#pragma unroll
                for (int r = 0; r < 4; ++r) {
                    float pv = __builtin_amdgcn_exp2f(sacc[i][j][r] * cs - mnew);
                    sacc[i][j][r] = pv;
                    rs += pv;
                }
            rs += __shfl_xor(rs, 16);
            rs += __shfl_xor(rs, 32);
            l[i] = l[i] * al + rs;
#pragma unroll
            for (int dt = 0; dt < 4; ++dt)
#pragma unroll
                for (int r = 0; r < 4; ++r) o_acc[i][dt][r] *= al;
        }

        __syncthreads();   // all waves done reading Ks -> KPs region reusable as P

        // ---- PV in two q halves; each wave owns rows [wave*16, wave*16+16) of P ----
#pragma unroll
        for (int i = 0; i < 2; ++i) {
#pragma unroll
            for (int j = 0; j < 4; ++j) {
                f16x4 pw;
#pragma unroll
                for (int r = 0; r < 4; ++r) pw[r] = (_Float16)sacc[i][j][r];
                *(f16x4*)&KPs[(wave * 16 + c) * LP + j * 16 + quad * 4] = pw;
            }
#pragma unroll
            for (int kt = 0; kt < 2; ++kt) {
                f16x8 pb = *(const f16x8*)&KPs[(wave * 16 + c) * LP + kt * 32 + quad * 8];
#pragma unroll
                for (int dt = 0; dt < 4; ++dt) {
                    f16x8 av = *(const f16x8*)&Vts[(dt * 16 + c) * LV + kt * 32 + quad * 8];
                    o_acc[i][dt] = __builtin_amdgcn_mfma_f32_16x16x32_f16(av, pb, o_acc[i][dt], 0, 0, 0);
                }
            }
        }
    }

    // ---- epilogue: O^T regs -> O[q][d], packed 8B stores ----
    _Float16* Og = O + (size_t)(b * SS + q0) * EE + h * DD;
#pragma unroll
    for (int i = 0; i < 2; ++i) {
        float inv = 1.0f / l[i];
#pragma unroll
        for (int dt = 0; dt < 4; ++dt) {
            f16x4 ov;
#pragma unroll
            for (int r = 0; r < 4; ++r) ov[r] = (_Float16)(o_acc[i][dt][r] * inv);
            *(f16x4*)&Og[(size_t)(wave * 32 + i * 16 + c) * EE + dt * 16 + quad * 4] = ov;
        }
    }
}

extern "C" void kernel_launch(void* const* d_in, const int* in_sizes, int n_in,
                              void* d_out, int out_size, void* d_ws, size_t ws_size,
                              hipStream_t stream) {
    const float* query = (const float*)d_in[0];
    const float* key   = (const float*)d_in[1];
    const float* value = (const float*)d_in[2];
    const float* Wq    = (const float*)d_in[3];
    const float* Wk    = (const float*)d_in[4];
    const float* Wv    = (const float*)d_in[5];
    const float* Wo    = (const float*)d_in[6];
    float* out = (float*)d_out;

    const size_t NE = (size_t)MM * EE;   // 8388608
    const size_t NW = (size_t)EE * EE;   // 1048576
    _Float16* buf0 = (_Float16*)d_ws;    // activation staging, later attn out (16MB)
    _Float16* Qw   = buf0 + NE;
    _Float16* Kw   = Qw + NE;
    _Float16* Vw   = Kw + NE;
    _Float16* wq   = Vw + NE;
    _Float16* wk   = wq + NW;
    _Float16* wv   = wk + NW;
    _Float16* wo   = wv + NW;            // total 72 MiB

    dim3 gg(MM / 128, EE / 128);   // 64 x 8
    dim3 blk(256);
    const int actN8 = (int)(NE / 8), wN8 = (int)(NW / 8);

    // weight converts
    cvt_kernel<<<wN8 / 256, blk, 0, stream>>>(Wq, wq, wN8);
    cvt_kernel<<<wN8 / 256, blk, 0, stream>>>(Wk, wk, wN8);
    cvt_kernel<<<wN8 / 256, blk, 0, stream>>>(Wv, wv, wN8);
    cvt_kernel<<<wN8 / 256, blk, 0, stream>>>(Wo, wo, wN8);

    // projections (activation convert reuses buf0; stream order serializes)
    cvt_kernel<<<actN8 / 256, blk, 0, stream>>>(query, buf0, actN8);
    gemm_bt_f16<_Float16><<<gg, blk, 0, stream>>>(buf0, wq, Qw, MM, EE, EE);
    cvt_kernel<<<actN8 / 256, blk, 0, stream>>>(key, buf0, actN8);
    gemm_bt_f16<_Float16><<<gg, blk, 0, stream>>>(buf0, wk, Kw, MM, EE, EE);
    cvt_kernel<<<actN8 / 256, blk, 0, stream>>>(value, buf0, actN8);
    gemm_bt_f16<_Float16><<<gg, blk, 0, stream>>>(buf0, wv, Vw, MM, EE, EE);

    // attention -> buf0 (free after V projection)
    attn_kernel<<<dim3(SS / 128, BB * HH), blk, 0, stream>>>(Qw, Kw, Vw, buf0);

    // output projection
    gemm_bt_f16<float><<<gg, blk, 0, stream>>>(buf0, wo, out, MM, EE, EE);
}